// Round 3
// baseline (31179.672 us; speedup 1.0000x reference)
//
#include <hip/hip_runtime.h>
#include <hip/hip_bf16.h>

typedef __attribute__((ext_vector_type(8))) short short8;
typedef __attribute__((ext_vector_type(4))) float f32x4;

#define T_STEPS 2048
#define NBATCH 64
#define HDIM 512
#define OUT_STRIDE (NBATCH * HDIM)   // 32768 elems per time slice
#define NGROUP 8
#define NSLICE 8
#define GROUP_ROWS 8
#define FLAG_STRIDE 2049
// d_ws layout: [0, 65568) flags; [128K, 256K) ring_hi; [256K, 384K) ring_lo
#define RING_HI_OFF (1u << 17)
#define RING_LO_OFF (1u << 18)

#define MFMA16 __builtin_amdgcn_mfma_f32_16x16x32_bf16

static __device__ __forceinline__ short f2bf(float f) {
    __hip_bfloat16 h = __float2bfloat16(f);
    return __builtin_bit_cast(short, h);
}
static __device__ __forceinline__ float bf2f(short s) {
    unsigned u = ((unsigned)(unsigned short)s) << 16;
    return __builtin_bit_cast(float, u);
}
// split f32 -> bf16 hi + bf16 lo (lo = bf16(x - hi)); exact for x = +-1.0
static __device__ __forceinline__ void split8v(f32x4 u, f32x4 v, short8& hi, short8& lo) {
#pragma unroll
    for (int j = 0; j < 4; ++j) { short h = f2bf(u[j]); hi[j] = h; lo[j] = f2bf(u[j] - bf2f(h)); }
#pragma unroll
    for (int j = 0; j < 4; ++j) { short h = f2bf(v[j]); hi[4 + j] = h; lo[4 + j] = f2bf(v[j] - bf2f(h)); }
}

// Persistent RNN, emulated-f32 precision via 3-term bf16 hi/lo MFMA.
// Grid 64 WGs = 8 batch-groups x 8 col-slices (all co-resident: 64 <= 256 CUs
// at launch_bounds(256,1)). h exchanged as bf16 hi/lo planes in a 2-slot ring
// in d_ws (producer-side split keeps conversion off the consumer path);
// per-(group,t) flag counters give release/acquire ordering (also WAR-safe
// for slot reuse: flag[g][t]=8 => all group-g readers of that slot's previous
// tenant finished, by read -> po -> release-flag -> acquire -> po -> write).
__global__ __launch_bounds__(256, 1) void rnn_persistent(
    const float* __restrict__ input,   // (2048, 64, 512) f32
    const float* __restrict__ weight,  // (1024, 512) f32: Wx rows 0..511, Wh rows 512..1023
    const float* __restrict__ bias,    // (512)
    const float* __restrict__ init_h,  // (512)
    float* __restrict__ out,           // (2049, 64, 512) f32
    unsigned char* __restrict__ ws)
{
    int*   flags   = (int*)ws;
    short* ring_hi = (short*)(ws + RING_HI_OFF);   // [2][64][512] bf16
    short* ring_lo = (short*)(ws + RING_LO_OFF);   // [2][64][512] bf16

    const int tid  = threadIdx.x;
    const int lane = tid & 63;
    const int wv   = tid >> 6;
    const int g    = blockIdx.x & 7;
    const int s    = blockIdx.x >> 3;
    const int r16  = lane & 15;
    const int kg   = lane >> 4;
    const int col  = s * 64 + wv * 16 + r16;
    const int brow = g * GROUP_ROWS + (r16 & 7);
    const int koff = kg * 8;

    // ---- one-time: weight column slices as hi/lo bf16 B-fragments (256 VGPR) ----
    short8 whb_hi[16], whb_lo[16], wxb_hi[16], wxb_lo[16];
#pragma unroll
    for (int c = 0; c < 16; ++c) {
        short8 xh, xl, hh, hl;
#pragma unroll
        for (int j = 0; j < 8; ++j) {
            const int k = c * 32 + koff + j;
            const float wx = weight[(size_t)k * HDIM + col];
            const float wh = weight[(size_t)(HDIM + k) * HDIM + col];
            short a = f2bf(wx); xh[j] = a; xl[j] = f2bf(wx - bf2f(a));
            short b = f2bf(wh); hh[j] = b; hl[j] = f2bf(wh - bf2f(b));
        }
        wxb_hi[c] = xh; wxb_lo[c] = xl; whb_hi[c] = hh; whb_lo[c] = hl;
    }
    const float bv = bias[col];

    // ---- out[0] = broadcast init_hidden (this WG's slice) ----
    for (int idx = tid; idx < GROUP_ROWS * 64; idx += 256) {
        const int rr = idx >> 6, cc = idx & 63;
        out[(size_t)(g * GROUP_ROWS + rr) * HDIM + s * 64 + cc] = init_h[s * 64 + cc];
    }

    // ---- xp(0) = bias + input[0] @ Wx, 3-chain hi/lo ----
    f32x4 xpA = {bv, bv, bv, bv}, xpB = {0, 0, 0, 0}, xpC = {0, 0, 0, 0};
    {
        const float* ip = input + (size_t)brow * HDIM;
#pragma unroll
        for (int c = 0; c < 16; ++c) {
            const int k0 = c * 32 + koff;
            f32x4 u = *(const f32x4*)(ip + k0);
            f32x4 v = *(const f32x4*)(ip + k0 + 4);
            short8 hi, lo; split8v(u, v, hi, lo);
            xpA = MFMA16(hi, wxb_hi[c], xpA, 0, 0, 0);
            xpB = MFMA16(lo, wxb_hi[c], xpB, 0, 0, 0);
            xpC = MFMA16(hi, wxb_lo[c], xpC, 0, 0, 0);
        }
    }

    for (int t = 0; t < T_STEPS; ++t) {
        // ---- wait for all 8 slices of h_t ----
        if (t > 0) {
            if (tid == 0) {
                while (__hip_atomic_load(&flags[g * FLAG_STRIDE + t], __ATOMIC_RELAXED,
                                         __HIP_MEMORY_SCOPE_AGENT) < NSLICE)
                    __builtin_amdgcn_s_sleep(1);
                __threadfence();   // acquire: inv L1/L2 so ring reads are fresh
            }
            __syncthreads();
        }

        // ---- A-fragments of h_t, hi/lo bf16 ----
        short8 ha_hi[16], ha_lo[16];
        if (t == 0) {
#pragma unroll
            for (int c = 0; c < 16; ++c) {
                const int k0 = c * 32 + koff;
                f32x4 u = *(const f32x4*)(init_h + k0);
                f32x4 v = *(const f32x4*)(init_h + k0 + 4);
                split8v(u, v, ha_hi[c], ha_lo[c]);
            }
        } else {
            const short* rh = ring_hi + (size_t)(t & 1) * OUT_STRIDE + (size_t)brow * HDIM;
            const short* rl = ring_lo + (size_t)(t & 1) * OUT_STRIDE + (size_t)brow * HDIM;
#pragma unroll
            for (int c = 0; c < 16; ++c) {
                const int k0 = c * 32 + koff;
                ha_hi[c] = *(const short8*)(rh + k0);
                ha_lo[c] = *(const short8*)(rl + k0);
            }
        }

        // ---- preact = xp(t) + h_t @ Wh, 3 independent chains ----
        f32x4 aA = xpA, aB = xpB, aC = xpC;
#pragma unroll
        for (int c = 0; c < 16; ++c) {
            aA = MFMA16(ha_hi[c], whb_hi[c], aA, 0, 0, 0);
            aB = MFMA16(ha_lo[c], whb_hi[c], aB, 0, 0, 0);
            aC = MFMA16(ha_hi[c], whb_lo[c], aC, 0, 0, 0);
        }

        const bool has_next = (t + 1 < T_STEPS);
        float hn[4];
#pragma unroll
        for (int r = 0; r < 4; ++r) hn[r] = tanhf(aA[r] + aB[r] + aC[r]);

        // ---- store h_{t+1}: f32 to out, hi/lo bf16 to ring slot (t+1)&1 ----
        if (kg < 2) {
            const size_t rowbase = (size_t)(g * GROUP_ROWS + kg * 4) * HDIM + col;
            float* op = out + (size_t)(t + 1) * OUT_STRIDE + rowbase;
            const int slot = (t + 1) & 1;
            short* ph = ring_hi + (size_t)slot * OUT_STRIDE + rowbase;
            short* pl = ring_lo + (size_t)slot * OUT_STRIDE + rowbase;
#pragma unroll
            for (int r = 0; r < 4; ++r) {
                op[r * HDIM] = hn[r];
                const short hh = f2bf(hn[r]);
                ph[r * HDIM] = hh;
                pl[r * HDIM] = f2bf(hn[r] - bf2f(hh));
            }
        }

        // ---- release: barrier (drains stores) -> fence (wbl2) -> flag ----
        __syncthreads();
        if (tid == 0 && has_next) {
            __threadfence();
            __hip_atomic_fetch_add(&flags[g * FLAG_STRIDE + t + 1], 1, __ATOMIC_RELAXED,
                                   __HIP_MEMORY_SCOPE_AGENT);
        }

        // ---- xp(t+1) in the slack, off the inter-WG critical path ----
        if (has_next) {
            const float* ip = input + (size_t)(t + 1) * OUT_STRIDE + (size_t)brow * HDIM;
            f32x4 nA = {bv, bv, bv, bv}, nB = {0, 0, 0, 0}, nC = {0, 0, 0, 0};
#pragma unroll
            for (int c = 0; c < 16; ++c) {
                const int k0 = c * 32 + koff;
                f32x4 u = *(const f32x4*)(ip + k0);
                f32x4 v = *(const f32x4*)(ip + k0 + 4);
                short8 hi, lo; split8v(u, v, hi, lo);
                nA = MFMA16(hi, wxb_hi[c], nA, 0, 0, 0);
                nB = MFMA16(lo, wxb_hi[c], nB, 0, 0, 0);
                nC = MFMA16(hi, wxb_lo[c], nC, 0, 0, 0);
            }
            xpA = nA; xpB = nB; xpC = nC;
        }
    }
}

extern "C" void kernel_launch(void* const* d_in, const int* in_sizes, int n_in,
                              void* d_out, int out_size, void* d_ws, size_t ws_size,
                              hipStream_t stream) {
    const float* input  = (const float*)d_in[0];
    const float* weight = (const float*)d_in[1];
    const float* biasp  = (const float*)d_in[2];
    const float* inith  = (const float*)d_in[3];
    float* out = (float*)d_out;

    // zero only the flag region each call (ring is re-written before reads)
    hipMemsetAsync(d_ws, 0, NGROUP * FLAG_STRIDE * sizeof(int), stream);

    rnn_persistent<<<dim3(NGROUP * NSLICE), dim3(256), 0, stream>>>(
        input, weight, biasp, inith, out, (unsigned char*)d_ws);
}